// Round 8
// baseline (261.408 us; speedup 1.0000x reference)
//
#include <hip/hip_runtime.h>
#include <math.h>
#include <stdint.h>

typedef __attribute__((ext_vector_type(8))) _Float16 half8;
typedef __attribute__((ext_vector_type(16))) float f32x16;
typedef __attribute__((ext_vector_type(4))) uint32_t uint4v;

constexpr int Bb = 8, Ll = 2500, Ee = 100, Nn = 8922;
constexpr int LP = 2560, EP = 128, NP = 8960;    // padded dims
constexpr int VE = 112;                          // staged V^T rows
constexpr int LT = 64;
constexpr int NTILES = LP / LT;                  // 40
constexpr int NTB = 128;                         // 4 waves x 32 n

constexpr size_t SZ_LF = (size_t)NP * EP * 2;
constexpr size_t SZ_XW = (size_t)Bb * LP * EP * 2;
constexpr size_t SZ_XT = (size_t)Bb * VE * LP * 2;
constexpr size_t OFF_XW = SZ_LF;
constexpr size_t OFF_XT = OFF_XW + SZ_XW;
constexpr size_t WS_NEED = OFF_XT + SZ_XT;       // ~12.14 MB (known-safe)

__device__ __forceinline__ void gload16(const void* g, void* l) {
    __builtin_amdgcn_global_load_lds(
        (const __attribute__((address_space(1))) uint32_t*)g,
        (__attribute__((address_space(3))) uint32_t*)l, 16, 0, 0);
}

// ---------- fused prepass (unchanged from R7) ----------
__global__ __launch_bounds__(256)
void prep_all(const float* __restrict__ x, const float* __restrict__ lf,
              uint32_t* __restrict__ dlf, uint32_t* __restrict__ dxw,
              uint16_t* __restrict__ dxt) {
    if (blockIdx.y == Bb) {
        for (int idx = blockIdx.x * 256 + threadIdx.x; idx < NP * 64; idx += 40 * 256) {
            int n = idx >> 6, ep = idx & 63;
            int e0 = 2 * ep, e1 = e0 + 1;
            float f0 = (n < Nn && e0 < Ee) ? lf[(size_t)n * Ee + e0] : 0.f;
            float f1 = (n < Nn && e1 < Ee) ? lf[(size_t)n * Ee + e1] : (e1 == 127 ? 1.0f : 0.f);
            union { _Float16 h[2]; uint32_t u; } cv;
            cv.h[0] = (_Float16)f0; cv.h[1] = (_Float16)f1;
            dlf[idx] = cv.u;
        }
        return;
    }
    __shared__ float lx[64][101];
    const int l0 = blockIdx.x * 64;
    const int b  = blockIdx.y;
    for (int i = threadIdx.x; i < 64 * Ee; i += 256) {
        int ll = i / Ee, e = i - ll * Ee;
        int l = l0 + ll;
        lx[ll][e] = (l < Ll) ? x[((size_t)b * Ll + l) * Ee + e] : 0.f;
    }
    __syncthreads();
    // K rows: 16B-chunk XOR key (l&15) within 256B row; mask bias at e=127
    for (int i = threadIdx.x; i < 64 * 64; i += 256) {
        int row = i >> 6, ep = i & 63;
        int l = l0 + row;
        int e0 = 2 * ep, e1 = e0 + 1;
        float f0 = (e0 < Ee) ? lx[row][e0] : 0.f;
        float f1;
        if (e1 < Ee)        f1 = lx[row][e1];
        else if (e1 == 127) f1 = (l < Ll) ? 0.f : -20000.f;   // softmax mask bias
        else                f1 = 0.f;
        union { _Float16 h[2]; uint32_t u; } cv;
        cv.h[0] = (_Float16)f0; cv.h[1] = (_Float16)f1;
        int boff = (4 * ep) ^ ((row & 15) << 4);
        dxw[((size_t)b * LP + l) * 64 + (boff >> 2)] = cv.u;
    }
    // V^T rows: [e][l], 16B-chunk XOR key (e&7) within each tile's 128B
    for (int i = threadIdx.x; i < VE * 64; i += 256) {
        int e = i >> 6, ll = i & 63;
        float v = (e < Ee) ? lx[ll][e] : 0.f;
        uint32_t boff = (uint32_t)((2 * ll) ^ ((e & 7) << 4));
        union { _Float16 h; uint16_t u; } cv; cv.h = (_Float16)v;
        dxt[((size_t)b * VE + e) * LP + l0 + (boff >> 1)] = cv.u;
    }
}

// ---------- main: 32x32 MFMA flash attention, K+V dbuf, issue-early/wait-late ----------
__global__ __launch_bounds__(256, 2)
void cwa_mfma(const uint16_t* __restrict__ lf16, const uint16_t* __restrict__ xw,
              const uint16_t* __restrict__ xt, float* __restrict__ out) {
    // K dbuf 2x16K @0 | V dbuf 2x14K @32768  => 60 KB
    __shared__ __align__(128) char smem[61440];
    const int tid = threadIdx.x, lane = tid & 63, w = tid >> 6;
    const int r31 = lane & 31, hi = lane >> 5;
    const int o = blockIdx.x;
    const int b = o & 7, xb = o >> 3;          // XCD swizzle: one batch per XCD
    const int n_base = xb * NTB + w * 32;

    const char* xwb = (const char*)(xw + (size_t)b * LP * EP);
    const char* xtb = (const char*)(xt + (size_t)b * VE * LP);

    auto stage_k = [&](int t, int p) {
        const char* kg = xwb + (size_t)t * (LT * EP * 2);
        char* kbuf = smem + p * 16384;
#pragma unroll
        for (int i = 0; i < 4; i++) {
            int off = i * 4096 + tid * 16;
            gload16(kg + off, kbuf + off);
        }
    };
    auto stage_v = [&](int t, int p) {
        const char* vg = xtb + (size_t)t * (LT * 2);
        char* vbuf = smem + 32768 + p * 14336;
#pragma unroll
        for (int i = 0; i < 3; i++) {
            int u = i * 256 + tid;
            gload16(vg + (size_t)(u >> 3) * (LP * 2) + (u & 7) * 16, vbuf + u * 16);
        }
        if (tid < 128) {
            int u = 768 + tid;
            gload16(vg + (size_t)(u >> 3) * (LP * 2) + (u & 7) * 16, vbuf + u * 16);
        }
    };

    // prologue: stage tile 0, load Q frags, wait, barrier
    stage_k(0, 0);
    stage_v(0, 0);
    half8 qf[8];
    {
        const uint16_t* qr = lf16 + (size_t)(n_base + r31) * EP + 8 * hi;
#pragma unroll
        for (int ks = 0; ks < 8; ks++) qf[ks] = *(const half8*)(qr + 16 * ks);
    }
    asm volatile("s_waitcnt vmcnt(0)" ::: "memory");
    __syncthreads();

    f32x16 oacc[4];
#pragma unroll
    for (int eb = 0; eb < 4; eb++)
#pragma unroll
        for (int r = 0; r < 16; r++) oacc[eb][r] = 0.f;
    float m_i = -INFINITY, s_i = 0.f;

    const int kkey = r31 & 15;    // K chunk XOR key
    const int vkey = r31 & 7;     // V chunk XOR key

    for (int t = 0; t < NTILES; t++) {
        const int p = t & 1;
        const char* kb = smem + p * 16384;
        const char* vb = smem + 32768 + p * 14336;

        // ---- issue-early: stage t+1 into the alternate buffers (freed by last barrier)
        if (t + 1 < NTILES) {
            stage_k(t + 1, p ^ 1);
            stage_v(t + 1, p ^ 1);
        }

        // ---- QK^T: S^T[l][n] = mfma(A=K, B=Q), 2 l-blocks x 8 k-steps ----
        f32x16 sacc[2];
#pragma unroll
        for (int lb = 0; lb < 2; lb++)
#pragma unroll
            for (int r = 0; r < 16; r++) sacc[lb][r] = 0.f;
        __builtin_amdgcn_s_setprio(1);
#pragma unroll
        for (int lb = 0; lb < 2; lb++) {
            const char* kr = kb + (32 * lb + r31) * 256;
#pragma unroll
            for (int ks = 0; ks < 8; ks++) {
                half8 kf = *(const half8*)(kr + (((2 * ks + hi) ^ kkey) << 4));
                sacc[lb] = __builtin_amdgcn_mfma_f32_32x32x16_f16(kf, qf[ks], sacc[lb], 0, 0, 0);
            }
        }
        __builtin_amdgcn_s_setprio(0);

        // ---- tile max over the lane's 32 l-values (balanced tree) ----
        float tmv;
        {
            float v0 = fmaxf(fmaxf(sacc[0][0], sacc[0][1]), fmaxf(sacc[0][2], sacc[0][3]));
            float v1 = fmaxf(fmaxf(sacc[0][4], sacc[0][5]), fmaxf(sacc[0][6], sacc[0][7]));
            float v2 = fmaxf(fmaxf(sacc[0][8], sacc[0][9]), fmaxf(sacc[0][10], sacc[0][11]));
            float v3 = fmaxf(fmaxf(sacc[0][12], sacc[0][13]), fmaxf(sacc[0][14], sacc[0][15]));
            float v4 = fmaxf(fmaxf(sacc[1][0], sacc[1][1]), fmaxf(sacc[1][2], sacc[1][3]));
            float v5 = fmaxf(fmaxf(sacc[1][4], sacc[1][5]), fmaxf(sacc[1][6], sacc[1][7]));
            float v6 = fmaxf(fmaxf(sacc[1][8], sacc[1][9]), fmaxf(sacc[1][10], sacc[1][11]));
            float v7 = fmaxf(fmaxf(sacc[1][12], sacc[1][13]), fmaxf(sacc[1][14], sacc[1][15]));
            tmv = fmaxf(fmaxf(fmaxf(v0, v1), fmaxf(v2, v3)),
                        fmaxf(fmaxf(v4, v5), fmaxf(v6, v7)));
            tmv = fmaxf(tmv, __shfl_xor(tmv, 32, 64));
        }

        // ---- defer-max (T13) ----
        if (!__all(tmv <= m_i + 8.f)) {
            const float mn = fmaxf(m_i, tmv);
            const float sc = __expf(m_i - mn);       // first tile: exp(-inf)=0
            m_i = mn;
            s_i *= sc;
#pragma unroll
            for (int r = 0; r < 16; r++) {
                float scr = __shfl(sc, (r & 3) + 8 * (r >> 2) + 4 * hi, 64);
#pragma unroll
                for (int eb = 0; eb < 4; eb++) oacc[eb][r] *= scr;
            }
        }

        // ---- P = exp(S - m); pack f16; in-register re-fragment; tree-sum ----
        half8 pa[4];
        float ts0 = 0.f, ts1 = 0.f, ts2 = 0.f, ts3 = 0.f;
#pragma unroll
        for (int lb = 0; lb < 2; lb++) {
            uint32_t c[8], xch[8];
#pragma unroll
            for (int i = 0; i < 8; i++) {
                float p0 = __expf(sacc[lb][2 * i]     - m_i);
                float p1 = __expf(sacc[lb][2 * i + 1] - m_i);
                switch (i & 3) {               // 4 parallel partial sums
                    case 0: ts0 += p0 + p1; break;
                    case 1: ts1 += p0 + p1; break;
                    case 2: ts2 += p0 + p1; break;
                    default: ts3 += p0 + p1; break;
                }
                c[i] = __builtin_bit_cast(uint32_t, __builtin_amdgcn_cvt_pkrtz(p0, p1));
            }
#pragma unroll
            for (int i = 0; i < 8; i++) xch[i] = __shfl_xor(c[i], 32, 64);
            uint4v wa = {hi ? xch[2] : c[0], hi ? xch[3] : c[1],
                         hi ? c[2] : xch[0], hi ? c[3] : xch[1]};
            uint4v wb2 = {hi ? xch[6] : c[4], hi ? xch[7] : c[5],
                          hi ? c[6] : xch[4], hi ? c[7] : xch[5]};
            pa[2 * lb]     = __builtin_bit_cast(half8, wa);
            pa[2 * lb + 1] = __builtin_bit_cast(half8, wb2);
        }
        float ts = (ts0 + ts1) + (ts2 + ts3);
        ts += __shfl_xor(ts, 32, 64);
        s_i += ts;

        // ---- PV: D[n][e] += mfma(A=P, B=V), 4 e-blocks x 4 k-steps ----
        __builtin_amdgcn_s_setprio(1);
#pragma unroll
        for (int eb = 0; eb < 4; eb++) {
            const char* vr = vb + (32 * eb + r31) * 128;
#pragma unroll
            for (int kk = 0; kk < 4; kk++) {
                half8 vf = *(const half8*)(vr + (((2 * kk + hi) ^ vkey) << 4));
                oacc[eb] = __builtin_amdgcn_mfma_f32_32x32x16_f16(pa[kk], vf, oacc[eb], 0, 0, 0);
            }
        }
        __builtin_amdgcn_s_setprio(0);

        // ---- wait-late: t+1's loads have been in flight under this whole tile ----
        asm volatile("s_waitcnt vmcnt(0)" ::: "memory");
        __syncthreads();
    }

    // ---- epilogue: out[b][n][e] = oacc/s ----
    const float inv = 1.0f / s_i;
#pragma unroll
    for (int r = 0; r < 16; r++) {
        const int nrow = (r & 3) + 8 * (r >> 2) + 4 * hi;
        const float invr = __shfl(inv, nrow, 64);
        const int n = n_base + nrow;
        if (n < Nn) {
            float* orow = out + ((size_t)b * Nn + n) * Ee;
            orow[r31]      = oacc[0][r] * invr;
            orow[32 + r31] = oacc[1][r] * invr;
            orow[64 + r31] = oacc[2][r] * invr;
            if (r31 < 4) orow[96 + r31] = oacc[3][r] * invr;
        }
    }
}

// ---------- fp32 fallback (verified R1 kernel) for ws too small ----------
constexpr int FNT = 16, FLT = 64, FLTP = 65;
__global__ __launch_bounds__(256)
void cwa_fwd(const float* __restrict__ x, const float* __restrict__ lf,
             float* __restrict__ out) {
    __shared__ float q[FNT][Ee];
    __shared__ float xts[Ee][FLTP];
    __shared__ float pl[FNT][FLT];
    const int tid = threadIdx.x, lane = tid & 63, w = tid >> 6;
    const int b = blockIdx.y, n0 = blockIdx.x * FNT;
    for (int idx = tid; idx < FNT * Ee; idx += 256) {
        int nl = idx / Ee, e = idx - nl * Ee;
        int n = n0 + nl;
        q[nl][e] = (n < Nn) ? lf[n * Ee + e] : 0.0f;
    }
    float m_i[4], s_i[4], a0[4], a1[4];
#pragma unroll
    for (int i = 0; i < 4; i++) { m_i[i] = -INFINITY; s_i[i] = 0.f; a0[i] = 0.f; a1[i] = 0.f; }
    const float* xb = x + (size_t)b * Ll * Ee;
    const bool hi_ok = lane < (Ee - 64);
    for (int l0 = 0; l0 < Ll; l0 += FLT) {
        const int nrows = min(FLT, Ll - l0);
        __syncthreads();
        for (int idx = tid; idx < FLT * (Ee / 4); idx += 256) {
            int r = idx / (Ee / 4), c4 = idx - r * (Ee / 4);
            float4 v = make_float4(0.f, 0.f, 0.f, 0.f);
            if (r < nrows) v = *reinterpret_cast<const float4*>(xb + (size_t)(l0 + r) * Ee + c4 * 4);
            xts[c4 * 4 + 0][r] = v.x; xts[c4 * 4 + 1][r] = v.y;
            xts[c4 * 4 + 2][r] = v.z; xts[c4 * 4 + 3][r] = v.w;
        }
        __syncthreads();
        float sc[4] = {0.f, 0.f, 0.f, 0.f};
        for (int e = 0; e < Ee; e++) {
            float xv = xts[e][lane];
#pragma unroll
            for (int i = 0; i < 4; i++) sc[i] = fmaf(q[4 * w + i][e], xv, sc[i]);
        }
        const bool valid = lane < nrows;
#pragma unroll
        for (int i = 0; i < 4; i++) {
            float s = valid ? sc[i] : -INFINITY;
            float tmv = s;
#pragma unroll
            for (int msk = 32; msk >= 1; msk >>= 1) tmv = fmaxf(tmv, __shfl_xor(tmv, msk, 64));
            float mn = fmaxf(m_i[i], tmv);
            float pp = __expf(s - mn);
            float sm = pp;
#pragma unroll
            for (int msk = 32; msk >= 1; msk >>= 1) sm += __shfl_xor(sm, msk, 64);
            float scl = __expf(m_i[i] - mn);
            s_i[i] = s_i[i] * scl + sm; m_i[i] = mn;
            a0[i] *= scl; a1[i] *= scl;
            pl[4 * w + i][lane] = pp;
        }
        __syncthreads();
#pragma unroll 4
        for (int l = 0; l < FLT; l++) {
            float xv0 = xts[lane][l];
            float xv1 = hi_ok ? xts[64 + lane][l] : 0.f;
#pragma unroll
            for (int i = 0; i < 4; i++) {
                float pv = pl[4 * w + i][l];
                a0[i] = fmaf(pv, xv0, a0[i]); a1[i] = fmaf(pv, xv1, a1[i]);
            }
        }
    }
#pragma unroll
    for (int i = 0; i < 4; i++) {
        int n = n0 + 4 * w + i;
        if (n >= Nn) continue;
        float inv = 1.0f / s_i[i];
        size_t base = ((size_t)b * Nn + n) * Ee;
        out[base + lane] = a0[i] * inv;
        if (hi_ok) out[base + 64 + lane] = a1[i] * inv;
    }
}

extern "C" void kernel_launch(void* const* d_in, const int* in_sizes, int n_in,
                              void* d_out, int out_size, void* d_ws, size_t ws_size,
                              hipStream_t stream) {
    const float* x  = (const float*)d_in[0];   // [8, 2500, 100]
    const float* lf = (const float*)d_in[1];   // [8922, 100]
    float* out = (float*)d_out;                // [8, 8922, 100]
    if (ws_size >= WS_NEED) {
        uint32_t* dlf = (uint32_t*)d_ws;
        uint32_t* dxw = (uint32_t*)((char*)d_ws + OFF_XW);
        uint16_t* dxt = (uint16_t*)((char*)d_ws + OFF_XT);
        prep_all<<<dim3(LP / 64, Bb + 1), 256, 0, stream>>>(x, lf, dlf, dxw, dxt);
        cwa_mfma<<<dim3((NP / NTB) * Bb), 256, 0, stream>>>(
            (const uint16_t*)dlf, (const uint16_t*)dxw, dxt, out);
    } else {
        dim3 grid((Nn + FNT - 1) / FNT, Bb);
        cwa_fwd<<<grid, dim3(256), 0, stream>>>(x, lf, out);
    }
}